// Round 2
// baseline (397.089 us; speedup 1.0000x reference)
//
#include <hip/hip_runtime.h>
#include <hip/hip_bf16.h>

// Problem constants
#define NN 245      // tokens
#define NP 256      // padded tokens
#define HH 12       // heads
#define DD 64       // head dim
#define CC 768      // channels
#define NBUCKET 1698
#define MROWS (64 * NN)   // 15680

#define BM 256
#define BN 256
#define BK 64
#define KTILES (CC / BK)   // 12

typedef __bf16 bf16x8 __attribute__((ext_vector_type(8)));
typedef float f32x4 __attribute__((ext_vector_type(4)));

#define MFMA(a, b, c) __builtin_amdgcn_mfma_f32_16x16x32_bf16(a, b, c, 0, 0, 0)

static __device__ __forceinline__ f32x4 fzero() {
    f32x4 z = {0.f, 0.f, 0.f, 0.f};
    return z;
}

static __device__ __forceinline__ bf16x8 cvt8(f32x4 lo, f32x4 hi) {
    bf16x8 r;
    #pragma unroll
    for (int i = 0; i < 4; ++i) { r[i] = (__bf16)lo[i]; r[i + 4] = (__bf16)hi[i]; }
    return r;
}

// async global->LDS, 16B per lane (wave-uniform LDS base + lane*16)
static __device__ __forceinline__ void gl_lds16(const __bf16* g, __bf16* l) {
    __builtin_amdgcn_global_load_lds(
        (const __attribute__((address_space(1))) void*)g,
        (__attribute__((address_space(3))) void*)l, 16, 0, 0);
}

// ---------------------------------------------------------------------------
// KC: fp32 -> bf16 bulk convert (n8 = elements/8)
__global__ __launch_bounds__(256) void kcvt(
    const float* __restrict__ src, __bf16* __restrict__ dst, int n8)
{
    int i = blockIdx.x * 256 + threadIdx.x;
    int stride = gridDim.x * 256;
    for (; i < n8; i += stride) {
        f32x4 a = *(const f32x4*)(src + (size_t)i * 8);
        f32x4 b = *(const f32x4*)(src + (size_t)i * 8 + 4);
        *(bf16x8*)(dst + (size_t)i * 8) = cvt8(a, b);
    }
}

// ---------------------------------------------------------------------------
// K0: bias'[g][n][m] = sum_h w_l[g,h] * rpe[h, rel_idx[n,m]] + b_l[g]
__global__ __launch_bounds__(256) void k0_bias(
    const float* __restrict__ rpe, const int* __restrict__ relidx,
    const float* __restrict__ wl_, const float* __restrict__ bl_,
    __bf16* __restrict__ biasb)
{
    __shared__ float wl[144];
    __shared__ float bl[12];
    int t = threadIdx.x;
    if (t < 144) wl[t] = wl_[t];
    if (t < 12)  bl[t] = bl_[t];
    __syncthreads();
    int n = blockIdx.x;   // 0..255
    int m = t;            // 0..255
    float r[12];
    bool valid = (n < NN) && (m < NN);
    if (valid) {
        int idx = relidx[n * NN + m];
        #pragma unroll
        for (int h = 0; h < 12; ++h) r[h] = rpe[h * NBUCKET + idx];
    }
    #pragma unroll
    for (int g = 0; g < 12; ++g) {
        float o = -30000.f;
        if (valid) {
            o = bl[g];
            #pragma unroll
            for (int h = 0; h < 12; ++h) o += wl[g * 12 + h] * r[h];
        }
        biasb[(size_t)(g * 256 + n) * 256 + m] = (__bf16)o;
    }
}

// ---------------------------------------------------------------------------
// gemm256: 256x256-tile NT GEMM, BK=64, 8 waves (2Mx4N), K-tile-granular
// double buffer (128KB LDS), counted vmcnt(8) (T4 - never drains to 0 in the
// main loop), raw s_barrier, T2 XOR-swizzle (inverse-swizzled global source +
// swizzled ds_read -> 2-way banks, free), T5 setprio around MFMA clusters,
// T1 XCD swizzle. Ported from the m201 8-phase template at K-tile phase
// granularity (K=768 is only 12 tiles).
//
// Schedule invariant: stage into slot s is issued only AFTER the barrier
// following the last ds_reads of slot s (reads already in registers);
// compute of tile t only after vmcnt guarantees its 8 loads landed in every
// wave (vmcnt(8) with exactly the next tile's 8 loads outstanding) + barrier.
template<int EPI>
__global__ __launch_bounds__(512, 2) void gemm256(
    const __bf16* __restrict__ A, const __bf16* __restrict__ Bw,
    __bf16* __restrict__ Q, __bf16* __restrict__ Kb, __bf16* __restrict__ VT,
    const float* __restrict__ bproj, float* __restrict__ outp)
{
    // [slot][mat: 0=A,1=B][256 rows][64 cols] bf16 = 128 KiB
    __shared__ __attribute__((aligned(16))) __bf16 lds[2][2][16384];

    int tid = threadIdx.x, lane = tid & 63, wave = tid >> 6;

    // T1: XCD-chunked bijective swizzle
    int gx = gridDim.x;
    int nwg = gx * gridDim.y;
    int wg = blockIdx.y * gx + blockIdx.x;
    int q8 = nwg >> 3, r8 = nwg & 7;
    int xcd = wg & 7, idx = wg >> 3;
    int swz = (xcd < r8 ? xcd * (q8 + 1) : r8 * (q8 + 1) + (xcd - r8) * q8) + idx;
    int et = swz % gx, mt = swz / gx;
    int m0 = mt * BM, e0 = et * BN;

    // ---- staging precompute: 4 x 16B chunks per thread per matrix --------
    // physical chunk c -> (row = c>>3, pcol = c&7); source col-group is the
    // inverse swizzle pcol ^ (row&7) so a swizzled read returns logical data.
    const __bf16* gA[4];
    const __bf16* gB[4];
    int cofs[4];
    #pragma unroll
    for (int j = 0; j < 4; ++j) {
        int c = tid + j * 512;
        int row = c >> 3, pcol = c & 7;
        int scol = pcol ^ (row & 7);
        int ga = m0 + row; if (ga > MROWS - 1) ga = MROWS - 1;
        gA[j] = A  + (size_t)ga * CC + scol * 8;
        gB[j] = Bw + (size_t)(e0 + row) * CC + scol * 8;
        cofs[j] = c * 8;
    }

    // ---- fragment-read offsets (bytes) -----------------------------------
    int wm = wave >> 2, wn = wave & 3;           // 2 M-groups x 4 N-groups
    int lrow = lane & 15, h = lane >> 4;
    int x0 = ((h)     ^ (lrow & 7)) * 16;        // ksub 0 swizzled slot
    int x1 = ((4 + h) ^ (lrow & 7)) * 16;        // ksub 1 swizzled slot
    int aoff = wm * 16384 + lrow * 128;          // wave's 128-row half of A
    int boff = wn * 8192  + lrow * 128;          // wave's 64-col slice of B

    f32x4 acc[8][4];
    #pragma unroll
    for (int q = 0; q < 8; ++q)
        #pragma unroll
        for (int n = 0; n < 4; ++n) acc[q][n] = fzero();

    #define STAGE(s, t) do {                                                  \
        int ko_ = (t) * BK;                                                   \
        _Pragma("unroll")                                                     \
        for (int j = 0; j < 4; ++j) gl_lds16(gA[j] + ko_, &lds[s][0][cofs[j]]);\
        _Pragma("unroll")                                                     \
        for (int j = 0; j < 4; ++j) gl_lds16(gB[j] + ko_, &lds[s][1][cofs[j]]);\
    } while (0)

    #define COMPUTE(s) do {                                                   \
        const char* bA_ = (const char*)(&lds[s][0][0]);                       \
        const char* bB_ = (const char*)(&lds[s][1][0]);                       \
        bf16x8 af[4][2], bfr[4][2];                                           \
        /* phase 1: qh0 x nh0 */                                              \
        _Pragma("unroll")                                                     \
        for (int q = 0; q < 4; ++q) {                                         \
            af[q][0] = *(const bf16x8*)(bA_ + aoff + q * 2048 + x0);          \
            af[q][1] = *(const bf16x8*)(bA_ + aoff + q * 2048 + x1);          \
        }                                                                     \
        _Pragma("unroll")                                                     \
        for (int n = 0; n < 2; ++n) {                                         \
            bfr[n][0] = *(const bf16x8*)(bB_ + boff + n * 2048 + x0);         \
            bfr[n][1] = *(const bf16x8*)(bB_ + boff + n * 2048 + x1);         \
        }                                                                     \
        __builtin_amdgcn_s_setprio(1);                                        \
        _Pragma("unroll")                                                     \
        for (int q = 0; q < 4; ++q)                                           \
            _Pragma("unroll")                                                 \
            for (int n = 0; n < 2; ++n) {                                     \
                acc[q][n] = MFMA(af[q][0], bfr[n][0], acc[q][n]);             \
                acc[q][n] = MFMA(af[q][1], bfr[n][1], acc[q][n]);             \
            }                                                                 \
        __builtin_amdgcn_s_setprio(0);                                        \
        /* phase 2: qh0 x nh1 */                                              \
        _Pragma("unroll")                                                     \
        for (int n = 2; n < 4; ++n) {                                         \
            bfr[n][0] = *(const bf16x8*)(bB_ + boff + n * 2048 + x0);         \
            bfr[n][1] = *(const bf16x8*)(bB_ + boff + n * 2048 + x1);         \
        }                                                                     \
        __builtin_amdgcn_s_setprio(1);                                        \
        _Pragma("unroll")                                                     \
        for (int q = 0; q < 4; ++q)                                           \
            _Pragma("unroll")                                                 \
            for (int n = 2; n < 4; ++n) {                                     \
                acc[q][n] = MFMA(af[q][0], bfr[n][0], acc[q][n]);             \
                acc[q][n] = MFMA(af[q][1], bfr[n][1], acc[q][n]);             \
            }                                                                 \
        __builtin_amdgcn_s_setprio(0);                                        \
        /* phase 3: qh1 x nh1 (reload A-frags) */                             \
        _Pragma("unroll")                                                     \
        for (int q = 0; q < 4; ++q) {                                         \
            af[q][0] = *(const bf16x8*)(bA_ + aoff + (q + 4) * 2048 + x0);    \
            af[q][1] = *(const bf16x8*)(bA_ + aoff + (q + 4) * 2048 + x1);    \
        }                                                                     \
        __builtin_amdgcn_s_setprio(1);                                        \
        _Pragma("unroll")                                                     \
        for (int q = 0; q < 4; ++q)                                           \
            _Pragma("unroll")                                                 \
            for (int n = 2; n < 4; ++n) {                                     \
                acc[q + 4][n] = MFMA(af[q][0], bfr[n][0], acc[q + 4][n]);     \
                acc[q + 4][n] = MFMA(af[q][1], bfr[n][1], acc[q + 4][n]);     \
            }                                                                 \
        __builtin_amdgcn_s_setprio(0);                                        \
        /* phase 4: qh1 x nh0 (reuse both) */                                 \
        __builtin_amdgcn_s_setprio(1);                                        \
        _Pragma("unroll")                                                     \
        for (int q = 0; q < 4; ++q)                                           \
            _Pragma("unroll")                                                 \
            for (int n = 0; n < 2; ++n) {                                     \
                acc[q + 4][n] = MFMA(af[q][0], bfr[n][0], acc[q + 4][n]);     \
                acc[q + 4][n] = MFMA(af[q][1], bfr[n][1], acc[q + 4][n]);     \
            }                                                                 \
        __builtin_amdgcn_s_setprio(0);                                        \
    } while (0)

    #define SBAR()     asm volatile("s_barrier" ::: "memory")
    #define VMCNT(n)   asm volatile("s_waitcnt vmcnt(" #n ")" ::: "memory")

    // prologue: tiles 0,1 in flight; wait tile 0
    STAGE(0, 0);
    STAGE(1, 1);
    VMCNT(8);
    SBAR();

    #pragma unroll 2
    for (int t = 0; t < KTILES - 2; ++t) {
        int s = t & 1;
        COMPUTE(s);
        SBAR();              // all waves done reading slot s
        STAGE(s, t + 2);     // overwrite slot s with tile t+2 (in flight)
        VMCNT(8);            // tile t+1's 8 loads landed (t+2's may fly)
        SBAR();              // ... in every wave
    }
    COMPUTE(0);              // t = 10 (slot 0)
    SBAR();
    VMCNT(0);                // tile 11 landed
    SBAR();
    COMPUTE(1);              // t = 11 (slot 1)

    #undef STAGE
    #undef COMPUTE
    #undef SBAR
    #undef VMCNT

    // ---- epilogue --------------------------------------------------------
    int col = lane & 15, rbs = h * 4;
    #pragma unroll
    for (int q = 0; q < 8; ++q) {
        int gmb = m0 + wm * 128 + q * 16 + rbs;
        #pragma unroll
        for (int n = 0; n < 4; ++n) {
            int e = e0 + wn * 64 + n * 16 + col;
            if (EPI == 0) {
                int which = e / CC;
                int hh2 = (e % CC) >> 6;
                int d = e & 63;
                #pragma unroll
                for (int r = 0; r < 4; ++r) {
                    int gm = gmb + r;
                    if (gm < MROWS) {
                        int bidx = gm / NN, nn2 = gm - bidx * NN;
                        float v = acc[q][n][r];
                        if (which == 0)
                            Q[((size_t)(bidx * 12 + hh2) * NP + nn2) * 64 + d] = (__bf16)(v * 0.125f);
                        else if (which == 1)
                            Kb[((size_t)(bidx * 12 + hh2) * NP + nn2) * 64 + d] = (__bf16)v;
                        else
                            VT[((size_t)(bidx * 12 + hh2) * 64 + d) * NP + nn2] = (__bf16)v;
                    }
                }
            } else {
                float bv = bproj[e];
                #pragma unroll
                for (int r = 0; r < 4; ++r) {
                    int gm = gmb + r;
                    if (gm < MROWS)
                        outp[(size_t)gm * CC + e] = acc[q][n][r] + bv;
                }
            }
        }
    }
}

// ---------------------------------------------------------------------------
// K2c: S[b][g][n][m] = sum_h w_l[g,h]*(q_h.k_h) + bias'[g][n][m]  (bf16)
__global__ __launch_bounds__(512, 4) void k2c_qk(
    const __bf16* __restrict__ Q, const __bf16* __restrict__ Kb,
    const __bf16* __restrict__ biasb, const float* __restrict__ wl_,
    __bf16* __restrict__ S)
{
    __shared__ float wl[144];
    int tid = threadIdx.x, wave = tid >> 6, lane = tid & 63;
    if (tid < 144) wl[tid] = wl_[tid];
    __syncthreads();

    // XCD swizzle: 2048 blocks, 8 consecutive b per XCD (32 blocks per b).
    int wg = blockIdx.x;
    int L = (wg & 7) * 256 + (wg >> 3);
    int b = L >> 5, rem = L & 31;
    int mq = rem & 3, nt = rem >> 2;          // mq 0..3, nt 0..7
    int wn = wave >> 2, wm = wave & 3;
    int n0 = nt * 32 + wn * 16;
    int m0 = mq * 64 + wm * 16;

    int lrow = lane & 15, lk = (lane >> 4) * 8;
    f32x4 acc[12];
    #pragma unroll
    for (int h = 0; h < 12; ++h) acc[h] = fzero();
    #pragma unroll
    for (int h = 0; h < 12; ++h) {
        const __bf16* qb = Q  + ((size_t)(b * 12 + h) * NP + n0 + lrow) * 64 + lk;
        const __bf16* kb = Kb + ((size_t)(b * 12 + h) * NP + m0 + lrow) * 64 + lk;
        bf16x8 a0 = *(const bf16x8*)qb;
        bf16x8 b0 = *(const bf16x8*)kb;
        bf16x8 a1 = *(const bf16x8*)(qb + 32);
        bf16x8 b1 = *(const bf16x8*)(kb + 32);
        acc[h] = MFMA(a0, b0, acc[h]);
        acc[h] = MFMA(a1, b1, acc[h]);
    }
    int col = lane & 15, rb = (lane >> 4) * 4;
    #pragma unroll
    for (int g = 0; g < 12; ++g) {
        f32x4 s = fzero();
        #pragma unroll
        for (int h = 0; h < 12; ++h) {
            float w = wl[g * 12 + h];
            s += acc[h] * w;
        }
        #pragma unroll
        for (int r = 0; r < 4; ++r) {
            int n = n0 + rb + r;
            int m = m0 + col;
            float v = s[r] + (float)biasb[(size_t)(g * 256 + n) * 256 + m];
            S[((size_t)(b * 12 + g) * NP + n) * NP + m] = (__bf16)v;
        }
    }
}

// ---------------------------------------------------------------------------
// K34 fused: softmax (P in registers) + w_w post-mix + PV MFMA.
__global__ __launch_bounds__(512, 3) void k34_smx_pv(
    const __bf16* __restrict__ S, const __bf16* __restrict__ VT,
    const float* __restrict__ ww_, const float* __restrict__ bw_,
    __bf16* __restrict__ aout)
{
    __shared__ __attribute__((aligned(16))) __bf16 Pp[2][16][264];
    __shared__ float ww[144];
    __shared__ float bw[12];
    int tid = threadIdx.x;
    if (tid < 144) ww[tid] = ww_[tid];
    if (tid >= 256 && tid < 268) bw[tid - 256] = bw_[tid - 256];

    // XCD swizzle: 16 same-b blocks -> same XCD
    int W = blockIdx.x;                 // 0..1023
    int g8 = W & 7, kk = W >> 3;
    int L = (kk >> 4) * 128 + g8 * 16 + (kk & 15);   // bijective
    int b = L >> 4, nt = L & 15;
    int n0 = nt * 16;

    int n = tid >> 5, ms = tid & 31;
    int lane = tid & 63, wave = tid >> 6;

    // ---- Phase A: per-(g,n)-row softmax; P kept in registers -------------
    float P[12][8];
    #pragma unroll
    for (int g = 0; g < 12; ++g) {
        const __bf16* rowp = S + ((size_t)(b * 12 + g) * NP + n0 + n) * NP + ms * 8;
        bf16x8 sv = *(const bf16x8*)rowp;
        float v[8];
        float mx = -1e30f;
        #pragma unroll
        for (int j = 0; j < 8; ++j) {
            v[j] = (ms * 8 + j < NN) ? (float)sv[j] : -1e30f;
            mx = fmaxf(mx, v[j]);
        }
        #pragma unroll
        for (int o = 16; o > 0; o >>= 1) mx = fmaxf(mx, __shfl_xor(mx, o));
        float sum = 0.f;
        #pragma unroll
        for (int j = 0; j < 8; ++j) {
            float e = (ms * 8 + j < NN) ? __expf(v[j] - mx) : 0.f;
            P[g][j] = e;
            sum += e;
        }
        #pragma unroll
        for (int o = 16; o > 0; o >>= 1) sum += __shfl_xor(sum, o);
        float inv = 1.f / sum;
        #pragma unroll
        for (int j = 0; j < 8; ++j) P[g][j] *= inv;
    }
    __syncthreads();   // also covers ww/bw loads

    // ---- Phase B: 6 chunks of {mix 2 gp -> LDS, PV MFMA} -----------------
    int dt = wave >> 1, wgp = wave & 1;
    int lrow = lane & 15, lk = (lane >> 4) * 8;
    int col = lane & 15, rb = (lane >> 4) * 4;
    #pragma unroll
    for (int c = 0; c < 6; ++c) {
        #pragma unroll
        for (int gi = 0; gi < 2; ++gi) {
            int gp = c * 2 + gi;
            bf16x8 o;
            #pragma unroll
            for (int j = 0; j < 8; ++j) {
                float a = bw[gp];
                #pragma unroll
                for (int g = 0; g < 12; ++g) a += ww[gp * 12 + g] * P[g][j];
                o[j] = (__bf16)((ms * 8 + j < NN) ? a : 0.f);
            }
            *(bf16x8*)&Pp[gi][n][ms * 8] = o;
        }
        __syncthreads();
        int gp = c * 2 + wgp;
        f32x4 acc = fzero();
        const __bf16* vb = VT + ((size_t)(b * 12 + gp) * 64 + dt * 16 + lrow) * NP + lk;
        #pragma unroll
        for (int kt = 0; kt < 8; ++kt) {
            bf16x8 av = *(const bf16x8*)&Pp[wgp][lrow][kt * 32 + lk];
            bf16x8 bv = *(const bf16x8*)(vb + kt * 32);
            acc = MFMA(av, bv, acc);
        }
        #pragma unroll
        for (int r = 0; r < 4; ++r) {
            int gn = n0 + rb + r;
            if (gn < NN)
                aout[((size_t)b * NN + gn) * CC + gp * 64 + dt * 16 + col] = (__bf16)acc[r];
        }
        __syncthreads();   // Pp consumed; safe to overwrite next chunk
    }
}

// ---------------------------------------------------------------------------
extern "C" void kernel_launch(void* const* d_in, const int* in_sizes, int n_in,
                              void* d_out, int out_size, void* d_ws, size_t ws_size,
                              hipStream_t stream)
{
    (void)in_sizes; (void)n_in; (void)out_size; (void)ws_size;
    const float* x     = (const float*)d_in[0];
    const float* wqkv  = (const float*)d_in[1];
    const float* wproj = (const float*)d_in[2];
    const float* bproj = (const float*)d_in[3];
    const float* wl    = (const float*)d_in[4];
    const float* bl    = (const float*)d_in[5];
    const float* ww    = (const float*)d_in[6];
    const float* bw    = (const float*)d_in[7];
    const float* rpe   = (const float*)d_in[8];
    const int*   rel   = (const int*)d_in[9];

    char* ws = (char*)d_ws;
    const size_t SZ_QKV = (size_t)64 * 12 * 256 * 64 * 2;   // 25,165,824 B
    const size_t SZ_S   = (size_t)64 * 12 * 256 * 256 * 2;  // 100,663,296 B
    __bf16* Q     = (__bf16*)(ws);
    __bf16* Kb    = (__bf16*)(ws + SZ_QKV);
    __bf16* VT    = (__bf16*)(ws + 2 * SZ_QKV);
    __bf16* biasb = (__bf16*)(ws + 3 * SZ_QKV);              // 1.5 MB (bf16)
    char*   sreg  = ws + 3 * SZ_QKV + (size_t)12 * 256 * 256 * 4;
    __bf16* S     = (__bf16*)sreg;
    // xb/wb alias into the S region (dead before k2c writes S)
    __bf16* xb    = (__bf16*)sreg;                               // 24.1 MB
    __bf16* wb    = (__bf16*)(sreg + (size_t)MROWS * CC * 2);    //  3.5 MB
    __bf16* wpb   = (__bf16*)(ws + 3 * SZ_QKV + (size_t)12 * 256 * 256 * 4 + SZ_S);
    __bf16* aout  = Q;  // Q dead after k2c; reuse as attn-out

    // zero VT so pad columns (m>=245) are 0 (P' is 0 there; avoid 0*NaN)
    hipMemsetAsync(VT, 0, SZ_QKV, stream);
    kcvt<<<dim3(2048), 256, 0, stream>>>(x,     xb,  MROWS * CC / 8);
    kcvt<<<dim3(864),  256, 0, stream>>>(wqkv,  wb,  3 * CC * CC / 8);
    kcvt<<<dim3(288),  256, 0, stream>>>(wproj, wpb, CC * CC / 8);
    k0_bias<<<dim3(256), 256, 0, stream>>>(rpe, rel, wl, bl, biasb);
    gemm256<0><<<dim3(9, 62), 512, 0, stream>>>(xb, wb, Q, Kb, VT, nullptr, nullptr);
    k2c_qk<<<dim3(2048), 512, 0, stream>>>(Q, Kb, biasb, wl, S);
    k34_smx_pv<<<dim3(1024), 512, 0, stream>>>(S, VT, ww, bw, aout);
    gemm256<1><<<dim3(3, 62), 512, 0, stream>>>(aout, wpb, nullptr, nullptr, nullptr,
                                                bproj, (float*)d_out);
}

// Round 6
// 390.944 us; speedup vs baseline: 1.0157x; 1.0157x over previous
//
#include <hip/hip_runtime.h>
#include <hip/hip_bf16.h>

// Problem constants
#define NN 245      // tokens
#define NP 256      // padded tokens
#define HH 12       // heads
#define DD 64       // head dim
#define CC 768      // channels
#define NBUCKET 1698
#define MROWS (64 * NN)   // 15680

typedef __bf16 bf16x8 __attribute__((ext_vector_type(8)));
typedef float f32x4 __attribute__((ext_vector_type(4)));

#define MFMA(a, b, c) __builtin_amdgcn_mfma_f32_16x16x32_bf16(a, b, c, 0, 0, 0)

static __device__ __forceinline__ f32x4 fzero() {
    f32x4 z = {0.f, 0.f, 0.f, 0.f};
    return z;
}

static __device__ __forceinline__ bf16x8 cvt8(f32x4 lo, f32x4 hi) {
    bf16x8 r;
    #pragma unroll
    for (int i = 0; i < 4; ++i) { r[i] = (__bf16)lo[i]; r[i + 4] = (__bf16)hi[i]; }
    return r;
}

// async global->LDS, 16B per lane (wave-uniform LDS base + lane*16)
static __device__ __forceinline__ void gl_lds16(const __bf16* g, __bf16* l) {
    __builtin_amdgcn_global_load_lds(
        (const __attribute__((address_space(1))) void*)g,
        (__attribute__((address_space(3))) void*)l, 16, 0, 0);
}

// ---------------------------------------------------------------------------
// KC: fp32 -> bf16 bulk convert (n8 = elements/8)
__global__ __launch_bounds__(256) void kcvt(
    const float* __restrict__ src, __bf16* __restrict__ dst, int n8)
{
    int i = blockIdx.x * 256 + threadIdx.x;
    int stride = gridDim.x * 256;
    for (; i < n8; i += stride) {
        f32x4 a = *(const f32x4*)(src + (size_t)i * 8);
        f32x4 b = *(const f32x4*)(src + (size_t)i * 8 + 4);
        *(bf16x8*)(dst + (size_t)i * 8) = cvt8(a, b);
    }
}

// ---------------------------------------------------------------------------
// K0: bias'[g][n][m] = sum_h w_l[g,h] * rpe[h, rel_idx[n,m]] + b_l[g]
//     Output bf16. Pad positions = -30000 so softmax zeroes them.
//     (R1-green version, reverted)
__global__ __launch_bounds__(256) void k0_bias(
    const float* __restrict__ rpe, const int* __restrict__ relidx,
    const float* __restrict__ wl_, const float* __restrict__ bl_,
    __bf16* __restrict__ biasb)
{
    __shared__ float wl[144];
    __shared__ float bl[12];
    int t = threadIdx.x;
    if (t < 144) wl[t] = wl_[t];
    if (t < 12)  bl[t] = bl_[t];
    __syncthreads();
    int n = blockIdx.x;   // 0..255
    int m = t;            // 0..255
    float r[12];
    bool valid = (n < NN) && (m < NN);
    if (valid) {
        int idx = relidx[n * NN + m];
        #pragma unroll
        for (int h = 0; h < 12; ++h) r[h] = rpe[h * NBUCKET + idx];
    }
    #pragma unroll
    for (int g = 0; g < 12; ++g) {
        float o = -30000.f;
        if (valid) {
            o = bl[g];
            #pragma unroll
            for (int h = 0; h < 12; ++h) o += wl[g * 12 + h] * r[h];
        }
        biasb[(size_t)(g * 256 + n) * 256 + m] = (__bf16)o;
    }
}

// ---------------------------------------------------------------------------
// gemm128: 128x128-tile NT GEMM (bf16 in, K=768), R6: BK=64 + T2 XOR-swizzle.
// Counter-driven: R0/R1 showed 6.8M SQ_LDS_BANK_CONFLICT (8-way on [128][32]
// ds_read_b128) and 24 vmcnt(0) barrier drains. BK=64 halves drain count
// (12 iters, 32 MFMA per drain); swizzle (verified-correct in R2's gemm256:
// conflicts measured 0) makes ds_read 2-way = free. Accumulation order is
// bitwise identical to R0 (same 24 k-steps in order); epilogue unchanged.
template<int EPI>
__global__ __launch_bounds__(256) void gemm128(
    const __bf16* __restrict__ A, const __bf16* __restrict__ Bw,
    __bf16* __restrict__ Q, __bf16* __restrict__ Kb, __bf16* __restrict__ VT,
    const float* __restrict__ bproj, float* __restrict__ outp)
{
    __shared__ __attribute__((aligned(16))) __bf16 sA[128 * 64];   // 16 KB
    __shared__ __attribute__((aligned(16))) __bf16 sB[128 * 64];   // 16 KB
    int tid = threadIdx.x, lane = tid & 63, wave = tid >> 6;

    // T1: XCD-chunked bijective swizzle
    int gx = gridDim.x;
    int nwg = gx * gridDim.y;
    int wg = blockIdx.y * gx + blockIdx.x;
    int q8 = nwg >> 3, r8 = nwg & 7;
    int xcd = wg & 7, idx = wg >> 3;
    int swz = (xcd < r8 ? xcd * (q8 + 1) : r8 * (q8 + 1) + (xcd - r8) * q8) + idx;
    int et = swz % gx, mt = swz / gx;
    int m0 = mt * 128, e0 = et * 128;

    // ---- staging: 4 x 16B chunks per thread per matrix (1024 chunks) -----
    // physical chunk c -> (row = c>>3, pcol = c&7); global source col-group
    // is the inverse swizzle pcol ^ (row&7), so swizzled reads return
    // logical data (R2-verified pattern).
    const __bf16* gA[4];
    const __bf16* gB[4];
    int cofs[4];
    #pragma unroll
    for (int j = 0; j < 4; ++j) {
        int c = tid + j * 256;
        int row = c >> 3, pcol = c & 7;
        int scol = pcol ^ (row & 7);
        int ga = m0 + row; if (ga >= MROWS) ga = MROWS - 1;
        gA[j] = A  + (size_t)ga * CC + scol * 8;
        gB[j] = Bw + (size_t)(e0 + row) * CC + scol * 8;
        cofs[j] = c * 8;
    }

    // ---- fragment-read offsets -------------------------------------------
    int wr = wave >> 1, wc = wave & 1;
    int lrow = lane & 15, h = lane >> 4;
    int x0 = ((h)     ^ (lrow & 7)) * 16;   // k-groups 0..3  (k 0..31)
    int x1 = ((h + 4) ^ (lrow & 7)) * 16;   // k-groups 4..7  (k 32..63)
    int aoff = (wr * 64 + lrow) * 128;      // byte offset, 128 B/row
    int boff = (wc * 64 + lrow) * 128;
    const char* bA = (const char*)sA;
    const char* bB = (const char*)sB;

    f32x4 acc[4][4];
    #pragma unroll
    for (int q = 0; q < 4; ++q)
        #pragma unroll
        for (int n = 0; n < 4; ++n) acc[q][n] = fzero();

    for (int it = 0; it < 12; ++it) {
        __syncthreads();
        #pragma unroll
        for (int j = 0; j < 4; ++j) gl_lds16(gA[j] + it * 64, sA + cofs[j]);
        #pragma unroll
        for (int j = 0; j < 4; ++j) gl_lds16(gB[j] + it * 64, sB + cofs[j]);
        __syncthreads();
        bf16x8 af0[4], af1[4], bf0[4], bf1[4];
        #pragma unroll
        for (int q = 0; q < 4; ++q) {
            af0[q] = *(const bf16x8*)(bA + aoff + q * 2048 + x0);
            af1[q] = *(const bf16x8*)(bA + aoff + q * 2048 + x1);
        }
        #pragma unroll
        for (int n = 0; n < 4; ++n) {
            bf0[n] = *(const bf16x8*)(bB + boff + n * 2048 + x0);
            bf1[n] = *(const bf16x8*)(bB + boff + n * 2048 + x1);
        }
        #pragma unroll
        for (int q = 0; q < 4; ++q)
            #pragma unroll
            for (int n = 0; n < 4; ++n)
                acc[q][n] = MFMA(af0[q], bf0[n], acc[q][n]);
        #pragma unroll
        for (int q = 0; q < 4; ++q)
            #pragma unroll
            for (int n = 0; n < 4; ++n)
                acc[q][n] = MFMA(af1[q], bf1[n], acc[q][n]);
    }

    int col = lane & 15, rbs = (lane >> 4) * 4;
    #pragma unroll
    for (int q = 0; q < 4; ++q) {
        int gmb = m0 + wr * 64 + q * 16 + rbs;
        #pragma unroll
        for (int n = 0; n < 4; ++n) {
            int e = e0 + wc * 64 + n * 16 + col;
            if (EPI == 0) {
                int which = e / CC;
                int hh = (e % CC) >> 6;
                int d = e & 63;
                #pragma unroll
                for (int r = 0; r < 4; ++r) {
                    int gm = gmb + r;
                    if (gm < MROWS) {
                        int bidx = gm / NN, nn = gm - bidx * NN;
                        float v = acc[q][n][r];
                        if (which == 0)
                            Q[((size_t)(bidx * 12 + hh) * NP + nn) * 64 + d] = (__bf16)(v * 0.125f);
                        else if (which == 1)
                            Kb[((size_t)(bidx * 12 + hh) * NP + nn) * 64 + d] = (__bf16)v;
                        else
                            VT[((size_t)(bidx * 12 + hh) * 64 + d) * NP + nn] = (__bf16)v;
                    }
                }
            } else {
                float bv = bproj[e];
                #pragma unroll
                for (int r = 0; r < 4; ++r) {
                    int gm = gmb + r;
                    if (gm < MROWS)
                        outp[(size_t)gm * CC + e] = acc[q][n][r] + bv;
                }
            }
        }
    }
}

// ---------------------------------------------------------------------------
// K2c: S[b][g][n][m] = sum_h w_l[g,h]*(q_h.k_h) + bias'[g][n][m]  (bf16)
// (R1-green version, reverted verbatim)
__global__ __launch_bounds__(512, 4) void k2c_qk(
    const __bf16* __restrict__ Q, const __bf16* __restrict__ Kb,
    const __bf16* __restrict__ biasb, const float* __restrict__ wl_,
    __bf16* __restrict__ S)
{
    __shared__ float wl[144];
    int tid = threadIdx.x, wave = tid >> 6, lane = tid & 63;
    if (tid < 144) wl[tid] = wl_[tid];
    __syncthreads();

    // XCD swizzle: 2048 blocks, 8 consecutive b per XCD (32 blocks per b).
    int wg = blockIdx.x;
    int L = (wg & 7) * 256 + (wg >> 3);
    int b = L >> 5, rem = L & 31;
    int mq = rem & 3, nt = rem >> 2;          // mq 0..3, nt 0..7
    int wn = wave >> 2, wm = wave & 3;
    int n0 = nt * 32 + wn * 16;
    int m0 = mq * 64 + wm * 16;

    int lrow = lane & 15, lk = (lane >> 4) * 8;
    f32x4 acc[12];
    #pragma unroll
    for (int h = 0; h < 12; ++h) acc[h] = fzero();
    #pragma unroll
    for (int h = 0; h < 12; ++h) {
        const __bf16* qb = Q  + ((size_t)(b * 12 + h) * NP + n0 + lrow) * 64 + lk;
        const __bf16* kb = Kb + ((size_t)(b * 12 + h) * NP + m0 + lrow) * 64 + lk;
        bf16x8 a0 = *(const bf16x8*)qb;
        bf16x8 b0 = *(const bf16x8*)kb;
        bf16x8 a1 = *(const bf16x8*)(qb + 32);
        bf16x8 b1 = *(const bf16x8*)(kb + 32);
        acc[h] = MFMA(a0, b0, acc[h]);
        acc[h] = MFMA(a1, b1, acc[h]);
    }
    int col = lane & 15, rb = (lane >> 4) * 4;
    #pragma unroll
    for (int g = 0; g < 12; ++g) {
        f32x4 s = fzero();
        #pragma unroll
        for (int h = 0; h < 12; ++h) {
            float w = wl[g * 12 + h];
            s += acc[h] * w;
        }
        #pragma unroll
        for (int r = 0; r < 4; ++r) {
            int n = n0 + rb + r;
            int m = m0 + col;
            float v = s[r] + (float)biasb[(size_t)(g * 256 + n) * 256 + m];
            S[((size_t)(b * 12 + g) * NP + n) * NP + m] = (__bf16)v;
        }
    }
}

// ---------------------------------------------------------------------------
// K34 fused: softmax (P in registers) + w_w post-mix + PV MFMA.
// (R1-green version, reverted verbatim)
__global__ __launch_bounds__(512, 3) void k34_smx_pv(
    const __bf16* __restrict__ S, const __bf16* __restrict__ VT,
    const float* __restrict__ ww_, const float* __restrict__ bw_,
    __bf16* __restrict__ aout)
{
    __shared__ __attribute__((aligned(16))) __bf16 Pp[2][16][264];
    __shared__ float ww[144];
    __shared__ float bw[12];
    int tid = threadIdx.x;
    if (tid < 144) ww[tid] = ww_[tid];
    if (tid >= 256 && tid < 268) bw[tid - 256] = bw_[tid - 256];

    // XCD swizzle: 16 same-b blocks -> same XCD
    int W = blockIdx.x;                 // 0..1023
    int g8 = W & 7, kk = W >> 3;
    int L = (kk >> 4) * 128 + g8 * 16 + (kk & 15);   // bijective
    int b = L >> 4, nt = L & 15;
    int n0 = nt * 16;

    int n = tid >> 5, ms = tid & 31;
    int lane = tid & 63, wave = tid >> 6;

    // ---- Phase A: per-(g,n)-row softmax; P kept in registers -------------
    float P[12][8];
    #pragma unroll
    for (int g = 0; g < 12; ++g) {
        const __bf16* rowp = S + ((size_t)(b * 12 + g) * NP + n0 + n) * NP + ms * 8;
        bf16x8 sv = *(const bf16x8*)rowp;
        float v[8];
        float mx = -1e30f;
        #pragma unroll
        for (int j = 0; j < 8; ++j) {
            v[j] = (ms * 8 + j < NN) ? (float)sv[j] : -1e30f;
            mx = fmaxf(mx, v[j]);
        }
        #pragma unroll
        for (int o = 16; o > 0; o >>= 1) mx = fmaxf(mx, __shfl_xor(mx, o));
        float sum = 0.f;
        #pragma unroll
        for (int j = 0; j < 8; ++j) {
            float e = (ms * 8 + j < NN) ? __expf(v[j] - mx) : 0.f;
            P[g][j] = e;
            sum += e;
        }
        #pragma unroll
        for (int o = 16; o > 0; o >>= 1) sum += __shfl_xor(sum, o);
        float inv = 1.f / sum;
        #pragma unroll
        for (int j = 0; j < 8; ++j) P[g][j] *= inv;
    }
    __syncthreads();   // also covers ww/bw loads

    // ---- Phase B: 6 chunks of {mix 2 gp -> LDS, PV MFMA} -----------------
    int dt = wave >> 1, wgp = wave & 1;
    int lrow = lane & 15, lk = (lane >> 4) * 8;
    int col = lane & 15, rb = (lane >> 4) * 4;
    #pragma unroll
    for (int c = 0; c < 6; ++c) {
        #pragma unroll
        for (int gi = 0; gi < 2; ++gi) {
            int gp = c * 2 + gi;
            bf16x8 o;
            #pragma unroll
            for (int j = 0; j < 8; ++j) {
                float a = bw[gp];
                #pragma unroll
                for (int g = 0; g < 12; ++g) a += ww[gp * 12 + g] * P[g][j];
                o[j] = (__bf16)((ms * 8 + j < NN) ? a : 0.f);
            }
            *(bf16x8*)&Pp[gi][n][ms * 8] = o;
        }
        __syncthreads();
        int gp = c * 2 + wgp;
        f32x4 acc = fzero();
        const __bf16* vb = VT + ((size_t)(b * 12 + gp) * 64 + dt * 16 + lrow) * NP + lk;
        #pragma unroll
        for (int kt = 0; kt < 8; ++kt) {
            bf16x8 av = *(const bf16x8*)&Pp[wgp][lrow][kt * 32 + lk];
            bf16x8 bv = *(const bf16x8*)(vb + kt * 32);
            acc = MFMA(av, bv, acc);
        }
        #pragma unroll
        for (int r = 0; r < 4; ++r) {
            int gn = n0 + rb + r;
            if (gn < NN)
                aout[((size_t)b * NN + gn) * CC + gp * 64 + dt * 16 + col] = (__bf16)acc[r];
        }
        __syncthreads();   // Pp consumed; safe to overwrite next chunk
    }
}

// ---------------------------------------------------------------------------
extern "C" void kernel_launch(void* const* d_in, const int* in_sizes, int n_in,
                              void* d_out, int out_size, void* d_ws, size_t ws_size,
                              hipStream_t stream)
{
    (void)in_sizes; (void)n_in; (void)out_size; (void)ws_size;
    const float* x     = (const float*)d_in[0];
    const float* wqkv  = (const float*)d_in[1];
    const float* wproj = (const float*)d_in[2];
    const float* bproj = (const float*)d_in[3];
    const float* wl    = (const float*)d_in[4];
    const float* bl    = (const float*)d_in[5];
    const float* ww    = (const float*)d_in[6];
    const float* bw    = (const float*)d_in[7];
    const float* rpe   = (const float*)d_in[8];
    const int*   rel   = (const int*)d_in[9];

    char* ws = (char*)d_ws;
    const size_t SZ_QKV = (size_t)64 * 12 * 256 * 64 * 2;   // 25,165,824 B
    const size_t SZ_S   = (size_t)64 * 12 * 256 * 256 * 2;  // 100,663,296 B
    __bf16* Q     = (__bf16*)(ws);
    __bf16* Kb    = (__bf16*)(ws + SZ_QKV);
    __bf16* VT    = (__bf16*)(ws + 2 * SZ_QKV);
    __bf16* biasb = (__bf16*)(ws + 3 * SZ_QKV);              // 1.5 MB (bf16)
    char*   sreg  = ws + 3 * SZ_QKV + (size_t)12 * 256 * 256 * 4;
    __bf16* S     = (__bf16*)sreg;
    // xb/wb alias into the S region (dead before k2c writes S)
    __bf16* xb    = (__bf16*)sreg;                               // 24.1 MB
    __bf16* wb    = (__bf16*)(sreg + (size_t)MROWS * CC * 2);    //  3.5 MB
    __bf16* wpb   = (__bf16*)(ws + 3 * SZ_QKV + (size_t)12 * 256 * 256 * 4 + SZ_S);
    __bf16* aout  = Q;  // Q dead after k2c; reuse as attn-out

    // zero VT so pad columns (m>=245) are 0 (P' is 0 there; avoid 0*NaN)
    hipMemsetAsync(VT, 0, SZ_QKV, stream);
    kcvt<<<dim3(2048), 256, 0, stream>>>(x,     xb,  MROWS * CC / 8);
    kcvt<<<dim3(864),  256, 0, stream>>>(wqkv,  wb,  3 * CC * CC / 8);
    kcvt<<<dim3(288),  256, 0, stream>>>(wproj, wpb, CC * CC / 8);
    k0_bias<<<dim3(256), 256, 0, stream>>>(rpe, rel, wl, bl, biasb);
    gemm128<0><<<dim3(18, 123), 256, 0, stream>>>(xb, wb, Q, Kb, VT, nullptr, nullptr);
    k2c_qk<<<dim3(2048), 512, 0, stream>>>(Q, Kb, biasb, wl, S);
    k34_smx_pv<<<dim3(1024), 512, 0, stream>>>(S, VT, ww, bw, aout);
    gemm128<1><<<dim3(6, 123), 256, 0, stream>>>(aout, wpb, nullptr, nullptr, nullptr,
                                                 bproj, (float*)d_out);
}

// Round 8
// 369.167 us; speedup vs baseline: 1.0756x; 1.0590x over previous
//
#include <hip/hip_runtime.h>
#include <hip/hip_bf16.h>

// Problem constants
#define NN 245      // tokens
#define NP 256      // padded tokens
#define HH 12       // heads
#define DD 64       // head dim
#define CC 768      // channels
#define NBUCKET 1698
#define MROWS (64 * NN)   // 15680

typedef __bf16 bf16x8 __attribute__((ext_vector_type(8)));
typedef float f32x4 __attribute__((ext_vector_type(4)));

#define MFMA(a, b, c) __builtin_amdgcn_mfma_f32_16x16x32_bf16(a, b, c, 0, 0, 0)

static __device__ __forceinline__ f32x4 fzero() {
    f32x4 z = {0.f, 0.f, 0.f, 0.f};
    return z;
}

static __device__ __forceinline__ bf16x8 cvt8(f32x4 lo, f32x4 hi) {
    bf16x8 r;
    #pragma unroll
    for (int i = 0; i < 4; ++i) { r[i] = (__bf16)lo[i]; r[i + 4] = (__bf16)hi[i]; }
    return r;
}

// async global->LDS, 16B per lane (wave-uniform LDS base + lane*16)
static __device__ __forceinline__ void gl_lds16(const __bf16* g, __bf16* l) {
    __builtin_amdgcn_global_load_lds(
        (const __attribute__((address_space(1))) void*)g,
        (__attribute__((address_space(3))) void*)l, 16, 0, 0);
}

// ---------------------------------------------------------------------------
// PREP (one launch, 3456 blocks of 256): the 4 independent prep tasks run
// concurrently instead of serialized across launches. Per-thread math is
// verbatim from the green kernels.
//   blocks [0,2048)    : x fp32->bf16     (grid-stride, n8 = MROWS*CC/8)
//   blocks [2048,2912) : wqkv fp32->bf16  (864 blocks, exact)
//   blocks [2912,3200) : wproj fp32->bf16 (288 blocks, exact)
//   blocks [3200,3456) : k0_bias          (256 blocks, n = bid-3200)
__global__ __launch_bounds__(256) void prep(
    const float* __restrict__ x,     __bf16* __restrict__ xb,
    const float* __restrict__ wqkv,  __bf16* __restrict__ wb,
    const float* __restrict__ wproj, __bf16* __restrict__ wpb,
    const float* __restrict__ rpe, const int* __restrict__ relidx,
    const float* __restrict__ wl_, const float* __restrict__ bl_,
    __bf16* __restrict__ biasb)
{
    __shared__ float wl[144];
    __shared__ float bl[12];
    int bid = blockIdx.x, t = threadIdx.x;

    if (bid < 2048) {
        const int n8 = MROWS * CC / 8;
        int i = bid * 256 + t;
        int stride = 2048 * 256;
        for (; i < n8; i += stride) {
            f32x4 a = *(const f32x4*)(x + (size_t)i * 8);
            f32x4 b = *(const f32x4*)(x + (size_t)i * 8 + 4);
            *(bf16x8*)(xb + (size_t)i * 8) = cvt8(a, b);
        }
    } else if (bid < 2912) {
        int i = (bid - 2048) * 256 + t;          // 864*256 == 3*CC*CC/8 exact
        f32x4 a = *(const f32x4*)(wqkv + (size_t)i * 8);
        f32x4 b = *(const f32x4*)(wqkv + (size_t)i * 8 + 4);
        *(bf16x8*)(wb + (size_t)i * 8) = cvt8(a, b);
    } else if (bid < 3200) {
        int i = (bid - 2912) * 256 + t;          // 288*256 == CC*CC/8 exact
        f32x4 a = *(const f32x4*)(wproj + (size_t)i * 8);
        f32x4 b = *(const f32x4*)(wproj + (size_t)i * 8 + 4);
        *(bf16x8*)(wpb + (size_t)i * 8) = cvt8(a, b);
    } else {
        // k0_bias verbatim (n = bid - 3200)
        if (t < 144) wl[t] = wl_[t];
        if (t < 12)  bl[t] = bl_[t];
        __syncthreads();
        int n = bid - 3200;   // 0..255
        int m = t;            // 0..255
        float r[12];
        bool valid = (n < NN) && (m < NN);
        if (valid) {
            int idx = relidx[n * NN + m];
            #pragma unroll
            for (int h = 0; h < 12; ++h) r[h] = rpe[h * NBUCKET + idx];
        }
        #pragma unroll
        for (int g = 0; g < 12; ++g) {
            float o = -30000.f;
            if (valid) {
                o = bl[g];
                #pragma unroll
                for (int h = 0; h < 12; ++h) o += wl[g * 12 + h] * r[h];
            }
            biasb[(size_t)(g * 256 + n) * 256 + m] = (__bf16)o;
        }
    }
}

// ---------------------------------------------------------------------------
// gemm128: m97-structure 128x128-tile NT GEMM (bf16 in, K=768, BK=32).
// R0-verified version verbatim (116.9 us green).
template<int EPI>
__global__ __launch_bounds__(256) void gemm128(
    const __bf16* __restrict__ A, const __bf16* __restrict__ Bw,
    __bf16* __restrict__ Q, __bf16* __restrict__ Kb, __bf16* __restrict__ VT,
    const float* __restrict__ bproj, float* __restrict__ outp)
{
    __shared__ __attribute__((aligned(16))) __bf16 sA[128 * 32];
    __shared__ __attribute__((aligned(16))) __bf16 sB[128 * 32];
    int tid = threadIdx.x, lane = tid & 63, wave = tid >> 6;

    // T1: XCD-chunked bijective swizzle
    int gx = gridDim.x;
    int nwg = gx * gridDim.y;
    int wg = blockIdx.y * gx + blockIdx.x;
    int q8 = nwg >> 3, r8 = nwg & 7;
    int xcd = wg & 7, idx = wg >> 3;
    int swz = (xcd < r8 ? xcd * (q8 + 1) : r8 * (q8 + 1) + (xcd - r8) * q8) + idx;
    int et = swz % gx, mt = swz / gx;
    int m0 = mt * 128, e0 = et * 128;

    int r1 = tid >> 2, chunk = tid & 3;
    int gar1 = m0 + r1;        if (gar1 >= MROWS) gar1 = MROWS - 1;
    int gar2 = m0 + 64 + r1;   if (gar2 >= MROWS) gar2 = MROWS - 1;
    const __bf16* aA1 = A  + (size_t)gar1 * CC + chunk * 8;
    const __bf16* aA2 = A  + (size_t)gar2 * CC + chunk * 8;
    const __bf16* aB1 = Bw + (size_t)(e0 + r1) * CC + chunk * 8;
    const __bf16* aB2 = Bw + (size_t)(e0 + 64 + r1) * CC + chunk * 8;
    __bf16* lA1 = sA + tid * 8;
    __bf16* lA2 = sA + tid * 8 + 2048;
    __bf16* lB1 = sB + tid * 8;
    __bf16* lB2 = sB + tid * 8 + 2048;

    int wr = wave >> 1, wc = wave & 1;
    int lrow = lane & 15, lk = (lane >> 4) * 8;
    const __bf16* ra = sA + (wr * 64 + lrow) * 32 + lk;
    const __bf16* rb = sB + (wc * 64 + lrow) * 32 + lk;

    f32x4 acc[4][4];
    #pragma unroll
    for (int q = 0; q < 4; ++q)
        #pragma unroll
        for (int n = 0; n < 4; ++n) acc[q][n] = fzero();

    for (int it = 0; it < 24; ++it) {
        __syncthreads();
        gl_lds16(aA1 + it * 32, lA1);
        gl_lds16(aA2 + it * 32, lA2);
        gl_lds16(aB1 + it * 32, lB1);
        gl_lds16(aB2 + it * 32, lB2);
        __syncthreads();
        bf16x8 af[4], bfr[4];
        #pragma unroll
        for (int q = 0; q < 4; ++q) af[q]  = *(const bf16x8*)(ra + q * 512);
        #pragma unroll
        for (int n = 0; n < 4; ++n) bfr[n] = *(const bf16x8*)(rb + n * 512);
        #pragma unroll
        for (int q = 0; q < 4; ++q)
            #pragma unroll
            for (int n = 0; n < 4; ++n)
                acc[q][n] = MFMA(af[q], bfr[n], acc[q][n]);
    }

    int col = lane & 15, rbs = (lane >> 4) * 4;
    #pragma unroll
    for (int q = 0; q < 4; ++q) {
        int gmb = m0 + wr * 64 + q * 16 + rbs;
        #pragma unroll
        for (int n = 0; n < 4; ++n) {
            int e = e0 + wc * 64 + n * 16 + col;
            if (EPI == 0) {
                int which = e / CC;
                int h = (e % CC) >> 6;
                int d = e & 63;
                #pragma unroll
                for (int r = 0; r < 4; ++r) {
                    int gm = gmb + r;
                    if (gm < MROWS) {
                        int bidx = gm / NN, nn = gm - bidx * NN;
                        float v = acc[q][n][r];
                        if (which == 0)
                            Q[((size_t)(bidx * 12 + h) * NP + nn) * 64 + d] = (__bf16)(v * 0.125f);
                        else if (which == 1)
                            Kb[((size_t)(bidx * 12 + h) * NP + nn) * 64 + d] = (__bf16)v;
                        else
                            VT[((size_t)(bidx * 12 + h) * 64 + d) * NP + nn] = (__bf16)v;
                    }
                }
            } else {
                float bv = bproj[e];
                #pragma unroll
                for (int r = 0; r < 4; ++r) {
                    int gm = gmb + r;
                    if (gm < MROWS)
                        outp[(size_t)gm * CC + e] = acc[q][n][r] + bv;
                }
            }
        }
    }
}

// ---------------------------------------------------------------------------
// K2c: S[b][g][n][m] = sum_h w_l[g,h]*(q_h.k_h) + bias'[g][n][m]  (bf16)
// (R1-green version verbatim)
__global__ __launch_bounds__(512, 4) void k2c_qk(
    const __bf16* __restrict__ Q, const __bf16* __restrict__ Kb,
    const __bf16* __restrict__ biasb, const float* __restrict__ wl_,
    __bf16* __restrict__ S)
{
    __shared__ float wl[144];
    int tid = threadIdx.x, wave = tid >> 6, lane = tid & 63;
    if (tid < 144) wl[tid] = wl_[tid];
    __syncthreads();

    // XCD swizzle: 2048 blocks, 8 consecutive b per XCD (32 blocks per b).
    int wg = blockIdx.x;
    int L = (wg & 7) * 256 + (wg >> 3);
    int b = L >> 5, rem = L & 31;
    int mq = rem & 3, nt = rem >> 2;          // mq 0..3, nt 0..7
    int wn = wave >> 2, wm = wave & 3;
    int n0 = nt * 32 + wn * 16;
    int m0 = mq * 64 + wm * 16;

    int lrow = lane & 15, lk = (lane >> 4) * 8;
    f32x4 acc[12];
    #pragma unroll
    for (int h = 0; h < 12; ++h) acc[h] = fzero();
    #pragma unroll
    for (int h = 0; h < 12; ++h) {
        const __bf16* qb = Q  + ((size_t)(b * 12 + h) * NP + n0 + lrow) * 64 + lk;
        const __bf16* kb = Kb + ((size_t)(b * 12 + h) * NP + m0 + lrow) * 64 + lk;
        bf16x8 a0 = *(const bf16x8*)qb;
        bf16x8 b0 = *(const bf16x8*)kb;
        bf16x8 a1 = *(const bf16x8*)(qb + 32);
        bf16x8 b1 = *(const bf16x8*)(kb + 32);
        acc[h] = MFMA(a0, b0, acc[h]);
        acc[h] = MFMA(a1, b1, acc[h]);
    }
    int col = lane & 15, rb = (lane >> 4) * 4;
    #pragma unroll
    for (int g = 0; g < 12; ++g) {
        f32x4 s = fzero();
        #pragma unroll
        for (int h = 0; h < 12; ++h) {
            float w = wl[g * 12 + h];
            s += acc[h] * w;
        }
        #pragma unroll
        for (int r = 0; r < 4; ++r) {
            int n = n0 + rb + r;
            int m = m0 + col;
            float v = s[r] + (float)biasb[(size_t)(g * 256 + n) * 256 + m];
            S[((size_t)(b * 12 + g) * NP + n) * NP + m] = (__bf16)v;
        }
    }
}

// ---------------------------------------------------------------------------
// K34 fused: softmax (P in registers) + w_w post-mix + PV MFMA.
// (R1-green version verbatim)
__global__ __launch_bounds__(512, 3) void k34_smx_pv(
    const __bf16* __restrict__ S, const __bf16* __restrict__ VT,
    const float* __restrict__ ww_, const float* __restrict__ bw_,
    __bf16* __restrict__ aout)
{
    __shared__ __attribute__((aligned(16))) __bf16 Pp[2][16][264];
    __shared__ float ww[144];
    __shared__ float bw[12];
    int tid = threadIdx.x;
    if (tid < 144) ww[tid] = ww_[tid];
    if (tid >= 256 && tid < 268) bw[tid - 256] = bw_[tid - 256];

    // XCD swizzle: 16 same-b blocks -> same XCD
    int W = blockIdx.x;                 // 0..1023
    int g8 = W & 7, kk = W >> 3;
    int L = (kk >> 4) * 128 + g8 * 16 + (kk & 15);   // bijective
    int b = L >> 4, nt = L & 15;
    int n0 = nt * 16;

    int n = tid >> 5, ms = tid & 31;
    int lane = tid & 63, wave = tid >> 6;

    // ---- Phase A: per-(g,n)-row softmax; P kept in registers -------------
    float P[12][8];
    #pragma unroll
    for (int g = 0; g < 12; ++g) {
        const __bf16* rowp = S + ((size_t)(b * 12 + g) * NP + n0 + n) * NP + ms * 8;
        bf16x8 sv = *(const bf16x8*)rowp;
        float v[8];
        float mx = -1e30f;
        #pragma unroll
        for (int j = 0; j < 8; ++j) {
            v[j] = (ms * 8 + j < NN) ? (float)sv[j] : -1e30f;
            mx = fmaxf(mx, v[j]);
        }
        #pragma unroll
        for (int o = 16; o > 0; o >>= 1) mx = fmaxf(mx, __shfl_xor(mx, o));
        float sum = 0.f;
        #pragma unroll
        for (int j = 0; j < 8; ++j) {
            float e = (ms * 8 + j < NN) ? __expf(v[j] - mx) : 0.f;
            P[g][j] = e;
            sum += e;
        }
        #pragma unroll
        for (int o = 16; o > 0; o >>= 1) sum += __shfl_xor(sum, o);
        float inv = 1.f / sum;
        #pragma unroll
        for (int j = 0; j < 8; ++j) P[g][j] *= inv;
    }
    __syncthreads();   // also covers ww/bw loads

    // ---- Phase B: 6 chunks of {mix 2 gp -> LDS, PV MFMA} -----------------
    int dt = wave >> 1, wgp = wave & 1;
    int lrow = lane & 15, lk = (lane >> 4) * 8;
    int col = lane & 15, rb = (lane >> 4) * 4;
    #pragma unroll
    for (int c = 0; c < 6; ++c) {
        #pragma unroll
        for (int gi = 0; gi < 2; ++gi) {
            int gp = c * 2 + gi;
            bf16x8 o;
            #pragma unroll
            for (int j = 0; j < 8; ++j) {
                float a = bw[gp];
                #pragma unroll
                for (int g = 0; g < 12; ++g) a += ww[gp * 12 + g] * P[g][j];
                o[j] = (__bf16)((ms * 8 + j < NN) ? a : 0.f);
            }
            *(bf16x8*)&Pp[gi][n][ms * 8] = o;
        }
        __syncthreads();
        int gp = c * 2 + wgp;
        f32x4 acc = fzero();
        const __bf16* vb = VT + ((size_t)(b * 12 + gp) * 64 + dt * 16 + lrow) * NP + lk;
        #pragma unroll
        for (int kt = 0; kt < 8; ++kt) {
            bf16x8 av = *(const bf16x8*)&Pp[wgp][lrow][kt * 32 + lk];
            bf16x8 bv = *(const bf16x8*)(vb + kt * 32);
            acc = MFMA(av, bv, acc);
        }
        #pragma unroll
        for (int r = 0; r < 4; ++r) {
            int gn = n0 + rb + r;
            if (gn < NN)
                aout[((size_t)b * NN + gn) * CC + gp * 64 + dt * 16 + col] = (__bf16)acc[r];
        }
        __syncthreads();   // Pp consumed; safe to overwrite next chunk
    }
}

// ---------------------------------------------------------------------------
extern "C" void kernel_launch(void* const* d_in, const int* in_sizes, int n_in,
                              void* d_out, int out_size, void* d_ws, size_t ws_size,
                              hipStream_t stream)
{
    (void)in_sizes; (void)n_in; (void)out_size; (void)ws_size;
    const float* x     = (const float*)d_in[0];
    const float* wqkv  = (const float*)d_in[1];
    const float* wproj = (const float*)d_in[2];
    const float* bproj = (const float*)d_in[3];
    const float* wl    = (const float*)d_in[4];
    const float* bl    = (const float*)d_in[5];
    const float* ww    = (const float*)d_in[6];
    const float* bw    = (const float*)d_in[7];
    const float* rpe   = (const float*)d_in[8];
    const int*   rel   = (const int*)d_in[9];

    char* ws = (char*)d_ws;
    const size_t SZ_QKV = (size_t)64 * 12 * 256 * 64 * 2;   // 25,165,824 B
    const size_t SZ_S   = (size_t)64 * 12 * 256 * 256 * 2;  // 100,663,296 B
    __bf16* Q     = (__bf16*)(ws);
    __bf16* Kb    = (__bf16*)(ws + SZ_QKV);
    __bf16* VT    = (__bf16*)(ws + 2 * SZ_QKV);
    __bf16* biasb = (__bf16*)(ws + 3 * SZ_QKV);              // 1.5 MB (bf16)
    char*   sreg  = ws + 3 * SZ_QKV + (size_t)12 * 256 * 256 * 4;
    __bf16* S     = (__bf16*)sreg;
    // xb/wb alias into the S region (dead before k2c writes S)
    __bf16* xb    = (__bf16*)sreg;                               // 24.1 MB
    __bf16* wb    = (__bf16*)(sreg + (size_t)MROWS * CC * 2);    //  3.5 MB
    __bf16* wpb   = (__bf16*)(ws + 3 * SZ_QKV + (size_t)12 * 256 * 256 * 4 + SZ_S);
    __bf16* aout  = Q;  // Q dead after k2c; reuse as attn-out

    // zero VT so pad columns (m>=245) are 0 (P' is 0 there; avoid 0*NaN)
    hipMemsetAsync(VT, 0, SZ_QKV, stream);
    prep<<<dim3(3456), 256, 0, stream>>>(x, xb, wqkv, wb, wproj, wpb,
                                         rpe, rel, wl, bl, biasb);
    gemm128<0><<<dim3(18, 123), 256, 0, stream>>>(xb, wb, Q, Kb, VT, nullptr, nullptr);
    k2c_qk<<<dim3(2048), 512, 0, stream>>>(Q, Kb, biasb, wl, S);
    k34_smx_pv<<<dim3(1024), 512, 0, stream>>>(S, VT, ww, bw, aout);
    gemm128<1><<<dim3(6, 123), 256, 0, stream>>>(aout, wpb, nullptr, nullptr, nullptr,
                                                 bproj, (float*)d_out);
}

// Round 10
// 361.220 us; speedup vs baseline: 1.0993x; 1.0220x over previous
//
#include <hip/hip_runtime.h>
#include <hip/hip_bf16.h>

// Problem constants
#define NN 245      // tokens
#define NP 256      // padded tokens
#define HH 12       // heads
#define DD 64       // head dim
#define CC 768      // channels
#define NBUCKET 1698
#define MROWS (64 * NN)   // 15680

typedef __bf16 bf16x8 __attribute__((ext_vector_type(8)));
typedef float f32x4 __attribute__((ext_vector_type(4)));

#define MFMA(a, b, c) __builtin_amdgcn_mfma_f32_16x16x32_bf16(a, b, c, 0, 0, 0)

static __device__ __forceinline__ f32x4 fzero() {
    f32x4 z = {0.f, 0.f, 0.f, 0.f};
    return z;
}

static __device__ __forceinline__ bf16x8 cvt8(f32x4 lo, f32x4 hi) {
    bf16x8 r;
    #pragma unroll
    for (int i = 0; i < 4; ++i) { r[i] = (__bf16)lo[i]; r[i + 4] = (__bf16)hi[i]; }
    return r;
}

// async global->LDS, 16B per lane (wave-uniform LDS base + lane*16)
static __device__ __forceinline__ void gl_lds16(const __bf16* g, __bf16* l) {
    __builtin_amdgcn_global_load_lds(
        (const __attribute__((address_space(1))) void*)g,
        (__attribute__((address_space(3))) void*)l, 16, 0, 0);
}

// ---------------------------------------------------------------------------
// PREP (one launch, 3648 blocks of 256): 4 independent prep tasks concurrent
// + VT pad-column zeroing (replaces the 25 MB hipMemsetAsync — only the pad
// columns nn in [245,256) are ever read-as-zero by k34's PV).
//   blocks [0,2048)    : x fp32->bf16     (grid-stride)
//   blocks [2048,2912) : wqkv fp32->bf16  (864 blocks, exact)
//   blocks [2912,3200) : wproj fp32->bf16 (288 blocks, exact)
//   blocks [3200,3456) : k0_bias          (256 blocks, n = bid-3200)
//   blocks [3456,3648) : VT pad zero      (192 blocks, 1 thread/row, 11 elems)
__global__ __launch_bounds__(256) void prep(
    const float* __restrict__ x,     __bf16* __restrict__ xb,
    const float* __restrict__ wqkv,  __bf16* __restrict__ wb,
    const float* __restrict__ wproj, __bf16* __restrict__ wpb,
    const float* __restrict__ rpe, const int* __restrict__ relidx,
    const float* __restrict__ wl_, const float* __restrict__ bl_,
    __bf16* __restrict__ biasb, __bf16* __restrict__ VT)
{
    __shared__ float wl[144];
    __shared__ float bl[12];
    int bid = blockIdx.x, t = threadIdx.x;

    if (bid < 2048) {
        const int n8 = MROWS * CC / 8;
        int i = bid * 256 + t;
        int stride = 2048 * 256;
        for (; i < n8; i += stride) {
            f32x4 a = *(const f32x4*)(x + (size_t)i * 8);
            f32x4 b = *(const f32x4*)(x + (size_t)i * 8 + 4);
            *(bf16x8*)(xb + (size_t)i * 8) = cvt8(a, b);
        }
    } else if (bid < 2912) {
        int i = (bid - 2048) * 256 + t;          // 864*256 == 3*CC*CC/8 exact
        f32x4 a = *(const f32x4*)(wqkv + (size_t)i * 8);
        f32x4 b = *(const f32x4*)(wqkv + (size_t)i * 8 + 4);
        *(bf16x8*)(wb + (size_t)i * 8) = cvt8(a, b);
    } else if (bid < 3200) {
        int i = (bid - 2912) * 256 + t;          // 288*256 == CC*CC/8 exact
        f32x4 a = *(const f32x4*)(wproj + (size_t)i * 8);
        f32x4 b = *(const f32x4*)(wproj + (size_t)i * 8 + 4);
        *(bf16x8*)(wpb + (size_t)i * 8) = cvt8(a, b);
    } else if (bid < 3456) {
        // k0_bias verbatim (n = bid - 3200)
        if (t < 144) wl[t] = wl_[t];
        if (t < 12)  bl[t] = bl_[t];
        __syncthreads();
        int n = bid - 3200;   // 0..255
        int m = t;            // 0..255
        float r[12];
        bool valid = (n < NN) && (m < NN);
        if (valid) {
            int idx = relidx[n * NN + m];
            #pragma unroll
            for (int h = 0; h < 12; ++h) r[h] = rpe[h * NBUCKET + idx];
        }
        #pragma unroll
        for (int g = 0; g < 12; ++g) {
            float o = -30000.f;
            if (valid) {
                o = bl[g];
                #pragma unroll
                for (int h = 0; h < 12; ++h) o += wl[g * 12 + h] * r[h];
            }
            biasb[(size_t)(g * 256 + n) * 256 + m] = (__bf16)o;
        }
    } else {
        // VT pad zero: rows are (b*12+h)*64+d, 0..49151; cols [245,256)
        int row = (bid - 3456) * 256 + t;        // 192*256 == 49152 exact
        __bf16* p = VT + (size_t)row * NP + NN;
        __bf16 z = (__bf16)0.f;
        #pragma unroll
        for (int j = 0; j < 11; ++j) p[j] = z;
    }
}

// ---------------------------------------------------------------------------
// gemm128: m97-structure 128x128-tile NT GEMM (bf16 in, K=768, BK=32).
// R0-verified version verbatim (116.9 us green, 3x). R9's counted-vmcnt
// pipeline raced (bare s_barrier after COMPUTE lets the compiler sink the
// ds_read lgkm waits past the barrier -> stale/new LDS mix); reverted.
template<int EPI>
__global__ __launch_bounds__(256) void gemm128(
    const __bf16* __restrict__ A, const __bf16* __restrict__ Bw,
    __bf16* __restrict__ Q, __bf16* __restrict__ Kb, __bf16* __restrict__ VT,
    const float* __restrict__ bproj, float* __restrict__ outp)
{
    __shared__ __attribute__((aligned(16))) __bf16 sA[128 * 32];
    __shared__ __attribute__((aligned(16))) __bf16 sB[128 * 32];
    int tid = threadIdx.x, lane = tid & 63, wave = tid >> 6;

    // T1: XCD-chunked bijective swizzle
    int gx = gridDim.x;
    int nwg = gx * gridDim.y;
    int wg = blockIdx.y * gx + blockIdx.x;
    int q8 = nwg >> 3, r8 = nwg & 7;
    int xcd = wg & 7, idx = wg >> 3;
    int swz = (xcd < r8 ? xcd * (q8 + 1) : r8 * (q8 + 1) + (xcd - r8) * q8) + idx;
    int et = swz % gx, mt = swz / gx;
    int m0 = mt * 128, e0 = et * 128;

    int r1 = tid >> 2, chunk = tid & 3;
    int gar1 = m0 + r1;        if (gar1 >= MROWS) gar1 = MROWS - 1;
    int gar2 = m0 + 64 + r1;   if (gar2 >= MROWS) gar2 = MROWS - 1;
    const __bf16* aA1 = A  + (size_t)gar1 * CC + chunk * 8;
    const __bf16* aA2 = A  + (size_t)gar2 * CC + chunk * 8;
    const __bf16* aB1 = Bw + (size_t)(e0 + r1) * CC + chunk * 8;
    const __bf16* aB2 = Bw + (size_t)(e0 + 64 + r1) * CC + chunk * 8;
    __bf16* lA1 = sA + tid * 8;
    __bf16* lA2 = sA + tid * 8 + 2048;
    __bf16* lB1 = sB + tid * 8;
    __bf16* lB2 = sB + tid * 8 + 2048;

    int wr = wave >> 1, wc = wave & 1;
    int lrow = lane & 15, lk = (lane >> 4) * 8;
    const __bf16* ra = sA + (wr * 64 + lrow) * 32 + lk;
    const __bf16* rb = sB + (wc * 64 + lrow) * 32 + lk;

    f32x4 acc[4][4];
    #pragma unroll
    for (int q = 0; q < 4; ++q)
        #pragma unroll
        for (int n = 0; n < 4; ++n) acc[q][n] = fzero();

    for (int it = 0; it < 24; ++it) {
        __syncthreads();
        gl_lds16(aA1 + it * 32, lA1);
        gl_lds16(aA2 + it * 32, lA2);
        gl_lds16(aB1 + it * 32, lB1);
        gl_lds16(aB2 + it * 32, lB2);
        __syncthreads();
        bf16x8 af[4], bfr[4];
        #pragma unroll
        for (int q = 0; q < 4; ++q) af[q]  = *(const bf16x8*)(ra + q * 512);
        #pragma unroll
        for (int n = 0; n < 4; ++n) bfr[n] = *(const bf16x8*)(rb + n * 512);
        #pragma unroll
        for (int q = 0; q < 4; ++q)
            #pragma unroll
            for (int n = 0; n < 4; ++n)
                acc[q][n] = MFMA(af[q], bfr[n], acc[q][n]);
    }

    int col = lane & 15, rbs = (lane >> 4) * 4;
    #pragma unroll
    for (int q = 0; q < 4; ++q) {
        int gmb = m0 + wr * 64 + q * 16 + rbs;
        #pragma unroll
        for (int n = 0; n < 4; ++n) {
            int e = e0 + wc * 64 + n * 16 + col;
            if (EPI == 0) {
                int which = e / CC;
                int h = (e % CC) >> 6;
                int d = e & 63;
                #pragma unroll
                for (int r = 0; r < 4; ++r) {
                    int gm = gmb + r;
                    if (gm < MROWS) {
                        int bidx = gm / NN, nn = gm - bidx * NN;
                        float v = acc[q][n][r];
                        if (which == 0)
                            Q[((size_t)(bidx * 12 + h) * NP + nn) * 64 + d] = (__bf16)(v * 0.125f);
                        else if (which == 1)
                            Kb[((size_t)(bidx * 12 + h) * NP + nn) * 64 + d] = (__bf16)v;
                        else
                            VT[((size_t)(bidx * 12 + h) * 64 + d) * NP + nn] = (__bf16)v;
                    }
                }
            } else {
                float bv = bproj[e];
                #pragma unroll
                for (int r = 0; r < 4; ++r) {
                    int gm = gmb + r;
                    if (gm < MROWS)
                        outp[(size_t)gm * CC + e] = acc[q][n][r] + bv;
                }
            }
        }
    }
}

// ---------------------------------------------------------------------------
// K2c: S[b][g][n][m] = sum_h w_l[g,h]*(q_h.k_h) + bias'[g][n][m]  (bf16)
// (R1-green version verbatim)
__global__ __launch_bounds__(512, 4) void k2c_qk(
    const __bf16* __restrict__ Q, const __bf16* __restrict__ Kb,
    const __bf16* __restrict__ biasb, const float* __restrict__ wl_,
    __bf16* __restrict__ S)
{
    __shared__ float wl[144];
    int tid = threadIdx.x, wave = tid >> 6, lane = tid & 63;
    if (tid < 144) wl[tid] = wl_[tid];
    __syncthreads();

    // XCD swizzle: 2048 blocks, 8 consecutive b per XCD (32 blocks per b).
    int wg = blockIdx.x;
    int L = (wg & 7) * 256 + (wg >> 3);
    int b = L >> 5, rem = L & 31;
    int mq = rem & 3, nt = rem >> 2;          // mq 0..3, nt 0..7
    int wn = wave >> 2, wm = wave & 3;
    int n0 = nt * 32 + wn * 16;
    int m0 = mq * 64 + wm * 16;

    int lrow = lane & 15, lk = (lane >> 4) * 8;
    f32x4 acc[12];
    #pragma unroll
    for (int h = 0; h < 12; ++h) acc[h] = fzero();
    #pragma unroll
    for (int h = 0; h < 12; ++h) {
        const __bf16* qb = Q  + ((size_t)(b * 12 + h) * NP + n0 + lrow) * 64 + lk;
        const __bf16* kb = Kb + ((size_t)(b * 12 + h) * NP + m0 + lrow) * 64 + lk;
        bf16x8 a0 = *(const bf16x8*)qb;
        bf16x8 b0 = *(const bf16x8*)kb;
        bf16x8 a1 = *(const bf16x8*)(qb + 32);
        bf16x8 b1 = *(const bf16x8*)(kb + 32);
        acc[h] = MFMA(a0, b0, acc[h]);
        acc[h] = MFMA(a1, b1, acc[h]);
    }
    int col = lane & 15, rb = (lane >> 4) * 4;
    #pragma unroll
    for (int g = 0; g < 12; ++g) {
        f32x4 s = fzero();
        #pragma unroll
        for (int h = 0; h < 12; ++h) {
            float w = wl[g * 12 + h];
            s += acc[h] * w;
        }
        #pragma unroll
        for (int r = 0; r < 4; ++r) {
            int n = n0 + rb + r;
            int m = m0 + col;
            float v = s[r] + (float)biasb[(size_t)(g * 256 + n) * 256 + m];
            S[((size_t)(b * 12 + g) * NP + n) * NP + m] = (__bf16)v;
        }
    }
}

// ---------------------------------------------------------------------------
// K34 fused: softmax (P in registers) + w_w post-mix + PV MFMA.
// (R1-green version verbatim)
__global__ __launch_bounds__(512, 3) void k34_smx_pv(
    const __bf16* __restrict__ S, const __bf16* __restrict__ VT,
    const float* __restrict__ ww_, const float* __restrict__ bw_,
    __bf16* __restrict__ aout)
{
    __shared__ __attribute__((aligned(16))) __bf16 Pp[2][16][264];
    __shared__ float ww[144];
    __shared__ float bw[12];
    int tid = threadIdx.x;
    if (tid < 144) ww[tid] = ww_[tid];
    if (tid >= 256 && tid < 268) bw[tid - 256] = bw_[tid - 256];

    // XCD swizzle: 16 same-b blocks -> same XCD
    int W = blockIdx.x;                 // 0..1023
    int g8 = W & 7, kk = W >> 3;
    int L = (kk >> 4) * 128 + g8 * 16 + (kk & 15);   // bijective
    int b = L >> 4, nt = L & 15;
    int n0 = nt * 16;

    int n = tid >> 5, ms = tid & 31;
    int lane = tid & 63, wave = tid >> 6;

    // ---- Phase A: per-(g,n)-row softmax; P kept in registers -------------
    float P[12][8];
    #pragma unroll
    for (int g = 0; g < 12; ++g) {
        const __bf16* rowp = S + ((size_t)(b * 12 + g) * NP + n0 + n) * NP + ms * 8;
        bf16x8 sv = *(const bf16x8*)rowp;
        float v[8];
        float mx = -1e30f;
        #pragma unroll
        for (int j = 0; j < 8; ++j) {
            v[j] = (ms * 8 + j < NN) ? (float)sv[j] : -1e30f;
            mx = fmaxf(mx, v[j]);
        }
        #pragma unroll
        for (int o = 16; o > 0; o >>= 1) mx = fmaxf(mx, __shfl_xor(mx, o));
        float sum = 0.f;
        #pragma unroll
        for (int j = 0; j < 8; ++j) {
            float e = (ms * 8 + j < NN) ? __expf(v[j] - mx) : 0.f;
            P[g][j] = e;
            sum += e;
        }
        #pragma unroll
        for (int o = 16; o > 0; o >>= 1) sum += __shfl_xor(sum, o);
        float inv = 1.f / sum;
        #pragma unroll
        for (int j = 0; j < 8; ++j) P[g][j] *= inv;
    }
    __syncthreads();   // also covers ww/bw loads

    // ---- Phase B: 6 chunks of {mix 2 gp -> LDS, PV MFMA} -----------------
    int dt = wave >> 1, wgp = wave & 1;
    int lrow = lane & 15, lk = (lane >> 4) * 8;
    int col = lane & 15, rb = (lane >> 4) * 4;
    #pragma unroll
    for (int c = 0; c < 6; ++c) {
        #pragma unroll
        for (int gi = 0; gi < 2; ++gi) {
            int gp = c * 2 + gi;
            bf16x8 o;
            #pragma unroll
            for (int j = 0; j < 8; ++j) {
                float a = bw[gp];
                #pragma unroll
                for (int g = 0; g < 12; ++g) a += ww[gp * 12 + g] * P[g][j];
                o[j] = (__bf16)((ms * 8 + j < NN) ? a : 0.f);
            }
            *(bf16x8*)&Pp[gi][n][ms * 8] = o;
        }
        __syncthreads();
        int gp = c * 2 + wgp;
        f32x4 acc = fzero();
        const __bf16* vb = VT + ((size_t)(b * 12 + gp) * 64 + dt * 16 + lrow) * NP + lk;
        #pragma unroll
        for (int kt = 0; kt < 8; ++kt) {
            bf16x8 av = *(const bf16x8*)&Pp[wgp][lrow][kt * 32 + lk];
            bf16x8 bv = *(const bf16x8*)(vb + kt * 32);
            acc = MFMA(av, bv, acc);
        }
        #pragma unroll
        for (int r = 0; r < 4; ++r) {
            int gn = n0 + rb + r;
            if (gn < NN)
                aout[((size_t)b * NN + gn) * CC + gp * 64 + dt * 16 + col] = (__bf16)acc[r];
        }
        __syncthreads();   // Pp consumed; safe to overwrite next chunk
    }
}

// ---------------------------------------------------------------------------
extern "C" void kernel_launch(void* const* d_in, const int* in_sizes, int n_in,
                              void* d_out, int out_size, void* d_ws, size_t ws_size,
                              hipStream_t stream)
{
    (void)in_sizes; (void)n_in; (void)out_size; (void)ws_size;
    const float* x     = (const float*)d_in[0];
    const float* wqkv  = (const float*)d_in[1];
    const float* wproj = (const float*)d_in[2];
    const float* bproj = (const float*)d_in[3];
    const float* wl    = (const float*)d_in[4];
    const float* bl    = (const float*)d_in[5];
    const float* ww    = (const float*)d_in[6];
    const float* bw    = (const float*)d_in[7];
    const float* rpe   = (const float*)d_in[8];
    const int*   rel   = (const int*)d_in[9];

    char* ws = (char*)d_ws;
    const size_t SZ_QKV = (size_t)64 * 12 * 256 * 64 * 2;   // 25,165,824 B
    const size_t SZ_S   = (size_t)64 * 12 * 256 * 256 * 2;  // 100,663,296 B
    __bf16* Q     = (__bf16*)(ws);
    __bf16* Kb    = (__bf16*)(ws + SZ_QKV);
    __bf16* VT    = (__bf16*)(ws + 2 * SZ_QKV);
    __bf16* biasb = (__bf16*)(ws + 3 * SZ_QKV);              // 1.5 MB (bf16)
    char*   sreg  = ws + 3 * SZ_QKV + (size_t)12 * 256 * 256 * 4;
    __bf16* S     = (__bf16*)sreg;
    // xb/wb alias into the S region (dead before k2c writes S)
    __bf16* xb    = (__bf16*)sreg;                               // 24.1 MB
    __bf16* wb    = (__bf16*)(sreg + (size_t)MROWS * CC * 2);    //  3.5 MB
    __bf16* wpb   = (__bf16*)(ws + 3 * SZ_QKV + (size_t)12 * 256 * 256 * 4 + SZ_S);
    __bf16* aout  = Q;  // Q dead after k2c; reuse as attn-out

    // VT pad columns zeroed inside prep (blocks [3456,3648)) — no memset.
    prep<<<dim3(3648), 256, 0, stream>>>(x, xb, wqkv, wb, wproj, wpb,
                                         rpe, rel, wl, bl, biasb, VT);
    gemm128<0><<<dim3(18, 123), 256, 0, stream>>>(xb, wb, Q, Kb, VT, nullptr, nullptr);
    k2c_qk<<<dim3(2048), 512, 0, stream>>>(Q, Kb, biasb, wl, S);
    k34_smx_pv<<<dim3(1024), 512, 0, stream>>>(S, VT, ww, bw, aout);
    gemm128<1><<<dim3(6, 123), 256, 0, stream>>>(aout, wpb, nullptr, nullptr, nullptr,
                                                 bproj, (float*)d_out);
}